// Round 9
// baseline (3269.770 us; speedup 1.0000x reference)
//
#include <hip/hip_runtime.h>
#include <hip/hip_bf16.h>
#include <stdint.h>
#include <stddef.h>

#define NPTS 8192
#define KNN  12
#define CH   128
#define FFD  512
#define MEDGE (NPTS * KNN)   // 98304 edges

typedef __attribute__((ext_vector_type(8))) _Float16 half8;
typedef __attribute__((ext_vector_type(4))) _Float16 half4;
typedef __attribute__((ext_vector_type(4))) float f32x4;

__device__ __forceinline__ float wave_sum(float v) {
#pragma unroll
  for (int off = 32; off > 0; off >>= 1) v += __shfl_xor(v, off, 64);
  return v;
}
__device__ __forceinline__ float sigm_(float x) { return 1.0f / (1.0f + expf(-x)); }
__device__ __forceinline__ float gelu_(float x) { return 0.5f * x * (1.0f + erff(x * 0.7071067811865475f)); }

// XOR-swizzled LDS chunk address (16B chunks, halfs): uniform <=2-way banks
#define XADDR(row, ch) ((((row) * 16 + ((ch) ^ ((row) & 7)))) * 8)

// ---------------------------------------------------------------------------
__global__ __launch_bounds__(256)
void prep_coords(const float* __restrict__ c, float4* __restrict__ c4)
{
  int i = blockIdx.x * 256 + threadIdx.x;
  if (i < NPTS) c4[i] = make_float4(c[3 * i], c[3 * i + 1], c[3 * i + 2], 0.0f);
}

// ---------------------------------------------------------------------------
// weight swizzle to MFMA A-fragment chunk order
// ---------------------------------------------------------------------------
struct SwzArgs {
  const float* src[8];
  _Float16* dst[8];
  int K[8], N[8], B[8], perB[8];
};

__global__ __launch_bounds__(256)
void prep_weights_swz(SwzArgs sa)
{
  int g = blockIdx.y;
  int idx = blockIdx.x * 256 + threadIdx.x;
  int perB = sa.perB[g];
  if (idx >= sa.B[g] * perB) return;
  int K = sa.K[g], N = sa.N[g];
  int b = idx / perB;
  int c = idx - b * perB;
  int l16 = c & 15;
  int quad = (c >> 4) & 3;
  int rest = c >> 6;
  int kts = K >> 5;
  int kt = rest % kts;
  int mt = rest / kts;
  const float* sp = sa.src[g] + ((size_t)b * K + kt * 32 + quad * 8) * N + mt * 16 + l16;
  _Float16* dp = sa.dst[g] + ((size_t)b * perB + c) * 8;
#pragma unroll
  for (int e = 0; e < 8; ++e) dp[e] = (_Float16)sp[(size_t)e * N];
}

// ---------------------------------------------------------------------------
// KNN via threshold filter + fused LN(s=0) -> nbr, v0 f32, xln0 (in gx)
// ---------------------------------------------------------------------------
#define KNN_CAP 2048

__global__ __launch_bounds__(256)
void knn_embed(const float4* __restrict__ coords4, const float* __restrict__ lng,
               const float* __restrict__ lnb, int* __restrict__ nbr,
               float* __restrict__ v0, _Float16* __restrict__ xln)
{
#pragma clang fp contract(off)
  __shared__ unsigned long long buf[KNN_CAP];
  __shared__ unsigned long long sel[KNN];
  __shared__ int cnt_s;
  const int i = blockIdx.x;
  const int tid = threadIdx.x;
  const int lane = tid & 63;
  const int wv = tid >> 6;
  const float4 ci = coords4[i];

  float T2 = 9.0f;
  int cnt;
  while (true) {
    if (tid == 0) cnt_s = 0;
    __syncthreads();
    for (int j = tid; j < NPTS; j += 256) {
      float4 cj = coords4[j];
      float dx = ci.x - cj.x;
      float dy = ci.y - cj.y;
      float dz = ci.z - cj.z;
      float d2 = dx * dx + dy * dy + dz * dz;   // contract off: matches numpy
      if (d2 < T2) {
        unsigned long long key =
            (((unsigned long long)__float_as_uint(sqrtf(d2))) << 32) | (unsigned int)j;
        int idx = atomicAdd(&cnt_s, 1);
        if (idx < KNN_CAP) buf[idx] = key;
      }
    }
    __syncthreads();
    cnt = cnt_s;
    if (cnt >= KNN) break;
    T2 *= 4.0f;
    __syncthreads();
  }
  if (cnt > KNN_CAP) cnt = KNN_CAP;

  if (wv == 0) {
    unsigned long long best[KNN];
#pragma unroll
    for (int q = 0; q < KNN; ++q) best[q] = ~0ULL;
    for (int p2 = lane; p2 < cnt; p2 += 64) {
      unsigned long long key = buf[p2];
      if (key < best[KNN - 1]) {
        best[KNN - 1] = key;
#pragma unroll
        for (int q = KNN - 2; q >= 0; --q) {
          if (best[q + 1] < best[q]) { unsigned long long t = best[q]; best[q] = best[q + 1]; best[q + 1] = t; }
        }
      }
    }
    int p = 0;
    for (int r = 0; r < KNN; ++r) {
      unsigned long long c = ~0ULL;
#pragma unroll
      for (int q = 0; q < KNN; ++q) if (q == p) c = best[q];
      unsigned long long m = c;
#pragma unroll
      for (int off = 32; off > 0; off >>= 1) {
        unsigned long long o = __shfl_xor(m, off, 64);
        if (o < m) m = o;
      }
      if (c == m) ++p;
      if (lane == 0) sel[r] = m;
    }
  }
  __syncthreads();
  if (tid < KNN) nbr[i * KNN + tid] = (int)(unsigned int)(sel[tid] & 0xFFFFFFFFULL);

  float g1 = lng[lane], g2 = lng[lane + 64];
  float bb1 = lnb[lane], bb2 = lnb[lane + 64];
  for (int k = wv * 3; k < wv * 3 + 3; ++k) {
    float d = __uint_as_float((unsigned int)(sel[k] >> 32));
    float sig1 = (float)(1.0 + 4.0 * (double)lane / 127.0);
    float sig2 = (float)(1.0 + 4.0 * (double)(lane + 64) / 127.0);
    float e1 = expf((-(d * d)) / (2.0f * sig1 * sig1));
    float e2 = expf((-(d * d)) / (2.0f * sig2 * sig2));
    float v1 = (e1 > 0.1f) ? e1 : 0.0f;
    float v2 = (e2 > 0.1f) ? e2 : 0.0f;
    size_t off = (size_t)(i * KNN + k) * CH;
    v0[off + lane] = v1;
    v0[off + lane + 64] = v2;
    float m = wave_sum(v1 + v2) * (1.0f / 128.0f);
    float d1 = v1 - m, d2 = v2 - m;
    float var = wave_sum(d1 * d1 + d2 * d2) * (1.0f / 128.0f);
    float rs = 1.0f / sqrtf(var + 1e-5f);
    xln[off + lane]      = (_Float16)(d1 * rs * g1 + bb1);
    xln[off + lane + 64] = (_Float16)(d2 * rs * g2 + bb2);
  }
}

// ---------------------------------------------------------------------------
__global__ __launch_bounds__(256)
void build_tidx(const int* __restrict__ nbr, int* __restrict__ tidx)
{
  int e = blockIdx.x * 256 + threadIdx.x;
  if (e >= MEDGE) return;
  int i = e / KNN;
  int j = nbr[e];
  int res = -1;
#pragma unroll
  for (int t = 0; t < KNN; ++t) {
    if (nbr[j * KNN + t] == i) { res = j * KNN + t; break; }
  }
  tidx[e] = res;
}

// ---------------------------------------------------------------------------
// init only: a, b, gob from xln. rt=2 streaming, 5 GEMMs.
// ---------------------------------------------------------------------------
__global__ __launch_bounds__(256)
void gemm_ab_go(const _Float16* __restrict__ xln,
                const _Float16* __restrict__ wa,  const float* __restrict__ ba,
                const _Float16* __restrict__ wga, const float* __restrict__ bga,
                const _Float16* __restrict__ wb,  const float* __restrict__ bb,
                const _Float16* __restrict__ wgb, const float* __restrict__ bgb,
                const _Float16* __restrict__ wgo, const float* __restrict__ bgo,
                _Float16* __restrict__ aout, _Float16* __restrict__ bout,
                _Float16* __restrict__ gobout)
{
  const int lane = threadIdx.x & 63;
  const int quad = lane >> 4;
  const int l16 = lane & 15;
  const int gw = blockIdx.x * 4 + (threadIdx.x >> 6);
  const int base = gw * 32;
  const int chbase = quad * 16 + l16;

  half8 xf[2][4];
#pragma unroll
  for (int rt = 0; rt < 2; ++rt)
#pragma unroll
    for (int kt = 0; kt < 4; ++kt)
      xf[rt][kt] = *(const half8*)(xln + (size_t)(base + rt * 16 + l16) * CH + kt * 32 + quad * 8);

  const half8* WA  = (const half8*)wa;
  const half8* WGA = (const half8*)wga;
  const half8* WB  = (const half8*)wb;
  const half8* WGB = (const half8*)wgb;
  const half8* WGO = (const half8*)wgo;

#pragma unroll
  for (int mt = 0; mt < 8; ++mt) {
    f32x4 aA[2], aGA[2], aB[2], aGB[2], aGO[2];
    const f32x4 z = {0.f, 0.f, 0.f, 0.f};
#pragma unroll
    for (int rt = 0; rt < 2; ++rt) { aA[rt] = z; aGA[rt] = z; aB[rt] = z; aGB[rt] = z; aGO[rt] = z; }
#pragma unroll
    for (int kt = 0; kt < 4; ++kt) {
      int ch = (mt * 4 + kt) * 64 + chbase;
      half8 wfa = WA[ch], wfga = WGA[ch], wfb = WB[ch], wfgb = WGB[ch], wfgo = WGO[ch];
#pragma unroll
      for (int rt = 0; rt < 2; ++rt) {
        aA[rt]  = __builtin_amdgcn_mfma_f32_16x16x32_f16(wfa,  xf[rt][kt], aA[rt], 0, 0, 0);
        aGA[rt] = __builtin_amdgcn_mfma_f32_16x16x32_f16(wfga, xf[rt][kt], aGA[rt], 0, 0, 0);
        aB[rt]  = __builtin_amdgcn_mfma_f32_16x16x32_f16(wfb,  xf[rt][kt], aB[rt], 0, 0, 0);
        aGB[rt] = __builtin_amdgcn_mfma_f32_16x16x32_f16(wfgb, xf[rt][kt], aGB[rt], 0, 0, 0);
        aGO[rt] = __builtin_amdgcn_mfma_f32_16x16x32_f16(wfgo, xf[rt][kt], aGO[rt], 0, 0, 0);
      }
    }
    f32x4 bva  = *(const f32x4*)(ba  + mt * 16 + quad * 4);
    f32x4 bvga = *(const f32x4*)(bga + mt * 16 + quad * 4);
    f32x4 bvb  = *(const f32x4*)(bb  + mt * 16 + quad * 4);
    f32x4 bvgb = *(const f32x4*)(bgb + mt * 16 + quad * 4);
    f32x4 bvgo = *(const f32x4*)(bgo + mt * 16 + quad * 4);
#pragma unroll
    for (int rt = 0; rt < 2; ++rt) {
      half4 av, bv, gv;
#pragma unroll
      for (int r = 0; r < 4; ++r) {
        av[r] = (_Float16)(sigm_(aGA[rt][r] + bvga[r]) * (aA[rt][r] + bva[r]));
        bv[r] = (_Float16)(sigm_(aGB[rt][r] + bvgb[r]) * (aB[rt][r] + bvb[r]));
        gv[r] = (_Float16)(sigm_(aGO[rt][r] + bvgo[r]));
      }
      size_t off = (size_t)(base + rt * 16 + l16) * CH + mt * 16 + quad * 4;
      *(half4*)(aout + off) = av;
      *(half4*)(bout + off) = bv;
      *(half4*)(gobout + off) = gv;
    }
  }
}

// ---------------------------------------------------------------------------
// tri einsum + LN -> klds ; og residual ; LN -> xsw (wave-local, swizzled) ;
// next a,b,gob GEMMs.  block = 4 n's = 48 rows, 192 thr / 3 waves.
// a/b outputs double-buffered vs inputs (cross-block gather WAR).
// ---------------------------------------------------------------------------
__global__ __launch_bounds__(192)
void tri_og_ab(const _Float16* __restrict__ a, const _Float16* __restrict__ b,
               const int* __restrict__ nbr, const int* __restrict__ tidx,
               const float* __restrict__ lng, const float* __restrict__ lnb,
               const _Float16* __restrict__ wo, const float* __restrict__ bo,
               const _Float16* __restrict__ gob, float* __restrict__ v,
               const float* __restrict__ nlng, const float* __restrict__ nlnb,
               const _Float16* __restrict__ wa,  const float* __restrict__ ba,
               const _Float16* __restrict__ wga, const float* __restrict__ bga,
               const _Float16* __restrict__ wb,  const float* __restrict__ bb,
               const _Float16* __restrict__ wgb, const float* __restrict__ bgb,
               const _Float16* __restrict__ wgo2, const float* __restrict__ bgo2,
               _Float16* __restrict__ aout, _Float16* __restrict__ bout,
               _Float16* __restrict__ gobout, int incoming)
{
  __shared__ alignas(16) _Float16 As[48][136];    // dot stage; reused as xsw
  __shared__ alignas(16) _Float16 klds[48][136];
  __shared__ int bidx[4][KNN][KNN];
  __shared__ int nbr_s[4][KNN];
  const int n0 = blockIdx.x * 4;
  const int tid = threadIdx.x;

  if (tid < 48) nbr_s[tid / KNN][tid % KNN] = nbr[n0 * KNN + tid];
  __syncthreads();
  for (int it = tid; it < 4 * KNN * KNN; it += 192) {
    int nn = it / (KNN * KNN);
    int r = it - nn * KNN * KNN;
    int m = r / KNN, t = r - m * KNN;
    int j = nbr_s[nn][m];
    bidx[nn][m][t] = incoming ? tidx[j * KNN + t] : (j * KNN + t);
  }
  for (int it = tid; it < 4 * KNN * 16; it += 192) {
    int nn = it / (KNN * 16);
    int r = it - nn * (KNN * 16);
    int t = r >> 4;
    int c8 = (r & 15) * 8;
    half8 av;
    if (incoming) {
      int ti = tidx[(size_t)(n0 + nn) * KNN + t];
      if (ti >= 0) av = *(const half8*)(a + (size_t)ti * CH + c8);
      else {
#pragma unroll
        for (int e = 0; e < 8; ++e) av[e] = (_Float16)0.0f;
      }
    } else {
      av = *(const half8*)(a + (size_t)((n0 + nn) * KNN + t) * CH + c8);
    }
    *(half8*)&As[nn * KNN + t][c8] = av;
  }
  __syncthreads();

  // dot + LN -> klds
  const int m2 = tid >> 4;
  const int c8 = (tid & 15) * 8;
  for (int nn = 0; nn < 4; ++nn) {
    float acc[8];
#pragma unroll
    for (int r = 0; r < 8; ++r) acc[r] = 0.0f;
#pragma unroll
    for (int t = 0; t < KNN; ++t) {
      int bi = bidx[nn][m2][t];
      if (bi >= 0) {
        half8 bv = *(const half8*)(b + (size_t)bi * CH + c8);
        half8 av = *(const half8*)&As[nn * KNN + t][c8];
#pragma unroll
        for (int r = 0; r < 8; ++r) acc[r] += (float)av[r] * (float)bv[r];
      }
    }
    float s = 0.0f, sq = 0.0f;
#pragma unroll
    for (int r = 0; r < 8; ++r) { s += acc[r]; sq += acc[r] * acc[r]; }
#pragma unroll
    for (int off = 1; off < 16; off <<= 1) {
      s += __shfl_xor(s, off, 64);
      sq += __shfl_xor(sq, off, 64);
    }
    float mean = s * (1.0f / 128.0f);
    float var = sq * (1.0f / 128.0f) - mean * mean;
    if (var < 0.0f) var = 0.0f;
    float rs = 1.0f / sqrtf(var + 1e-5f);
    half8 o;
#pragma unroll
    for (int r = 0; r < 8; ++r)
      o[r] = (_Float16)((acc[r] - mean) * rs * lng[c8 + r] + lnb[c8 + r]);
    *(half8*)&klds[nn * KNN + m2][c8] = o;
  }
  __syncthreads();   // klds ready; As free after this point

  // og phase
  const int lane = tid & 63;
  const int w = tid >> 6;
  const int quad = lane >> 4;
  const int l16 = lane & 15;
  const int chbase = quad * 16 + l16;
  const int rowL = w * 16 + l16;
  const size_t rowOff = (size_t)(blockIdx.x * 48 + rowL) * CH;
  _Float16* xsw = &As[0][0];

  half8 kf[4];
#pragma unroll
  for (int kt = 0; kt < 4; ++kt)
    kf[kt] = *(const half8*)&klds[rowL][kt * 32 + quad * 8];

  const half8* WO = (const half8*)wo;
  f32x4 vn[8];
  float s = 0.0f, sq = 0.0f;
#pragma unroll
  for (int mt = 0; mt < 8; ++mt) {
    f32x4 acc = {0.f, 0.f, 0.f, 0.f};
#pragma unroll
    for (int kt = 0; kt < 4; ++kt)
      acc = __builtin_amdgcn_mfma_f32_16x16x32_f16(WO[(mt * 4 + kt) * 64 + chbase], kf[kt], acc, 0, 0, 0);
    half4 g4 = *(const half4*)(gob + rowOff + mt * 16 + quad * 4);
    f32x4 bo4 = *(const f32x4*)(bo + mt * 16 + quad * 4);
    f32x4 vv = *(const f32x4*)(v + rowOff + mt * 16 + quad * 4);
#pragma unroll
    for (int r = 0; r < 4; ++r) {
      float nv = vv[r] + (float)g4[r] * (acc[r] + bo4[r]);
      vn[mt][r] = nv;
      s += nv;
      sq += nv * nv;
    }
    *(f32x4*)(v + rowOff + mt * 16 + quad * 4) = vn[mt];
  }
  s  += __shfl_xor(s, 16, 64);  s  += __shfl_xor(s, 32, 64);
  sq += __shfl_xor(sq, 16, 64); sq += __shfl_xor(sq, 32, 64);
  float mean = s * (1.0f / 128.0f);
  float var = sq * (1.0f / 128.0f) - mean * mean;
  if (var < 0.0f) var = 0.0f;
  float rs = 1.0f / sqrtf(var + 1e-5f);
  // LN -> xsw (wave-local rows; no barrier needed)
#pragma unroll
  for (int mt = 0; mt < 8; ++mt) {
    f32x4 g4 = *(const f32x4*)(nlng + mt * 16 + quad * 4);
    f32x4 b4 = *(const f32x4*)(nlnb + mt * 16 + quad * 4);
    half4 o;
#pragma unroll
    for (int r = 0; r < 4; ++r)
      o[r] = (_Float16)((vn[mt][r] - mean) * rs * g4[r] + b4[r]);
    int ch = mt * 2 + (quad >> 1);
    *(half4*)&xsw[XADDR(rowL, ch) + (quad & 1) * 4] = o;
  }
  // ab phase (wave-local frag reads)
  half8 xf[4];
#pragma unroll
  for (int kt = 0; kt < 4; ++kt)
    xf[kt] = *(const half8*)&xsw[XADDR(rowL, kt * 4 + quad)];

  const half8* WA  = (const half8*)wa;
  const half8* WGA = (const half8*)wga;
  const half8* WB  = (const half8*)wb;
  const half8* WGB = (const half8*)wgb;
  const half8* WGO = (const half8*)wgo2;
#pragma unroll
  for (int mt = 0; mt < 8; ++mt) {
    f32x4 aA = {0.f,0.f,0.f,0.f}, aGA = aA, aB = aA, aGB = aA, aGO = aA;
#pragma unroll
    for (int kt = 0; kt < 4; ++kt) {
      int ch = (mt * 4 + kt) * 64 + chbase;
      aA  = __builtin_amdgcn_mfma_f32_16x16x32_f16(WA[ch],  xf[kt], aA, 0, 0, 0);
      aGA = __builtin_amdgcn_mfma_f32_16x16x32_f16(WGA[ch], xf[kt], aGA, 0, 0, 0);
      aB  = __builtin_amdgcn_mfma_f32_16x16x32_f16(WB[ch],  xf[kt], aB, 0, 0, 0);
      aGB = __builtin_amdgcn_mfma_f32_16x16x32_f16(WGB[ch], xf[kt], aGB, 0, 0, 0);
      aGO = __builtin_amdgcn_mfma_f32_16x16x32_f16(WGO[ch], xf[kt], aGO, 0, 0, 0);
    }
    f32x4 bva  = *(const f32x4*)(ba   + mt * 16 + quad * 4);
    f32x4 bvga = *(const f32x4*)(bga  + mt * 16 + quad * 4);
    f32x4 bvb  = *(const f32x4*)(bb   + mt * 16 + quad * 4);
    f32x4 bvgb = *(const f32x4*)(bgb  + mt * 16 + quad * 4);
    f32x4 bvgo = *(const f32x4*)(bgo2 + mt * 16 + quad * 4);
    half4 av, bv, gv;
#pragma unroll
    for (int r = 0; r < 4; ++r) {
      av[r] = (_Float16)(sigm_(aGA[r] + bvga[r]) * (aA[r] + bva[r]));
      bv[r] = (_Float16)(sigm_(aGB[r] + bvgb[r]) * (aB[r] + bvb[r]));
      gv[r] = (_Float16)(sigm_(aGO[r] + bvgo[r]));
    }
    size_t off = rowOff + mt * 16 + quad * 4;
    *(half4*)(aout + off) = av;
    *(half4*)(bout + off) = bv;
    *(half4*)(gobout + off) = gv;
  }
}

// ---------------------------------------------------------------------------
// tri einsum + LN -> klds ; og residual ; xln write (for ffn).  R8 kernel.
// ---------------------------------------------------------------------------
__global__ __launch_bounds__(192)
void tri_og(const _Float16* __restrict__ a, const _Float16* __restrict__ b,
            const int* __restrict__ nbr, const int* __restrict__ tidx,
            const float* __restrict__ lng, const float* __restrict__ lnb,
            const _Float16* __restrict__ wo, const float* __restrict__ bo,
            const _Float16* __restrict__ gob, float* __restrict__ v,
            const float* __restrict__ nlng, const float* __restrict__ nlnb,
            _Float16* __restrict__ xlnN, int incoming)
{
  __shared__ alignas(16) _Float16 As[48][136];
  __shared__ alignas(16) _Float16 klds[48][136];
  __shared__ int bidx[4][KNN][KNN];
  __shared__ int nbr_s[4][KNN];
  const int n0 = blockIdx.x * 4;
  const int tid = threadIdx.x;

  if (tid < 48) nbr_s[tid / KNN][tid % KNN] = nbr[n0 * KNN + tid];
  __syncthreads();
  for (int it = tid; it < 4 * KNN * KNN; it += 192) {
    int nn = it / (KNN * KNN);
    int r = it - nn * KNN * KNN;
    int m = r / KNN, t = r - m * KNN;
    int j = nbr_s[nn][m];
    bidx[nn][m][t] = incoming ? tidx[j * KNN + t] : (j * KNN + t);
  }
  for (int it = tid; it < 4 * KNN * 16; it += 192) {
    int nn = it / (KNN * 16);
    int r = it - nn * (KNN * 16);
    int t = r >> 4;
    int c8 = (r & 15) * 8;
    half8 av;
    if (incoming) {
      int ti = tidx[(size_t)(n0 + nn) * KNN + t];
      if (ti >= 0) av = *(const half8*)(a + (size_t)ti * CH + c8);
      else {
#pragma unroll
        for (int e = 0; e < 8; ++e) av[e] = (_Float16)0.0f;
      }
    } else {
      av = *(const half8*)(a + (size_t)((n0 + nn) * KNN + t) * CH + c8);
    }
    *(half8*)&As[nn * KNN + t][c8] = av;
  }
  __syncthreads();

  const int m2 = tid >> 4;
  const int c8 = (tid & 15) * 8;
  for (int nn = 0; nn < 4; ++nn) {
    float acc[8];
#pragma unroll
    for (int r = 0; r < 8; ++r) acc[r] = 0.0f;
#pragma unroll
    for (int t = 0; t < KNN; ++t) {
      int bi = bidx[nn][m2][t];
      if (bi >= 0) {
        half8 bv = *(const half8*)(b + (size_t)bi * CH + c8);
        half8 av = *(const half8*)&As[nn * KNN + t][c8];
#pragma unroll
        for (int r = 0; r < 8; ++r) acc[r] += (float)av[r] * (float)bv[r];
      }
    }
    float s = 0.0f, sq = 0.0f;
#pragma unroll
    for (int r = 0; r < 8; ++r) { s += acc[r]; sq += acc[r] * acc[r]; }
#pragma unroll
    for (int off = 1; off < 16; off <<= 1) {
      s += __shfl_xor(s, off, 64);
      sq += __shfl_xor(sq, off, 64);
    }
    float mean = s * (1.0f / 128.0f);
    float var = sq * (1.0f / 128.0f) - mean * mean;
    if (var < 0.0f) var = 0.0f;
    float rs = 1.0f / sqrtf(var + 1e-5f);
    half8 o;
#pragma unroll
    for (int r = 0; r < 8; ++r)
      o[r] = (_Float16)((acc[r] - mean) * rs * lng[c8 + r] + lnb[c8 + r]);
    *(half8*)&klds[nn * KNN + m2][c8] = o;
  }
  __syncthreads();

  const int lane = tid & 63;
  const int w = tid >> 6;
  const int quad = lane >> 4;
  const int l16 = lane & 15;
  const int chbase = quad * 16 + l16;
  const size_t rowOff = (size_t)(blockIdx.x * 48 + w * 16 + l16) * CH;

  half8 kf[4];
#pragma unroll
  for (int kt = 0; kt < 4; ++kt)
    kf[kt] = *(const half8*)&klds[w * 16 + l16][kt * 32 + quad * 8];

  const half8* WO = (const half8*)wo;
  f32x4 vn[8];
  float s = 0.0f, sq = 0.0f;
#pragma unroll
  for (int mt = 0; mt < 8; ++mt) {
    f32x4 acc = {0.f, 0.f, 0.f, 0.f};
#pragma unroll
    for (int kt = 0; kt < 4; ++kt)
      acc = __builtin_amdgcn_mfma_f32_16x16x32_f16(WO[(mt * 4 + kt) * 64 + chbase], kf[kt], acc, 0, 0, 0);
    half4 g4 = *(const half4*)(gob + rowOff + mt * 16 + quad * 4);
    f32x4 bo4 = *(const f32x4*)(bo + mt * 16 + quad * 4);
    f32x4 vv = *(const f32x4*)(v + rowOff + mt * 16 + quad * 4);
#pragma unroll
    for (int r = 0; r < 4; ++r) {
      float nv = vv[r] + (float)g4[r] * (acc[r] + bo4[r]);
      vn[mt][r] = nv;
      s += nv;
      sq += nv * nv;
    }
    *(f32x4*)(v + rowOff + mt * 16 + quad * 4) = vn[mt];
  }
  s  += __shfl_xor(s, 16, 64);  s  += __shfl_xor(s, 32, 64);
  sq += __shfl_xor(sq, 16, 64); sq += __shfl_xor(sq, 32, 64);
  float mean = s * (1.0f / 128.0f);
  float var = sq * (1.0f / 128.0f) - mean * mean;
  if (var < 0.0f) var = 0.0f;
  float rs = 1.0f / sqrtf(var + 1e-5f);
#pragma unroll
  for (int mt = 0; mt < 8; ++mt) {
    f32x4 g4 = *(const f32x4*)(nlng + mt * 16 + quad * 4);
    f32x4 b4 = *(const f32x4*)(nlnb + mt * 16 + quad * 4);
    half4 o;
#pragma unroll
    for (int r = 0; r < 4; ++r)
      o[r] = (_Float16)((vn[mt][r] - mean) * rs * g4[r] + b4[r]);
    *(half4*)(xlnN + rowOff + mt * 16 + quad * 4) = o;
  }
}

// ---------------------------------------------------------------------------
// fused FFN + next a,b,gob: h in XOR-swizzled LDS; v += h@W2 + b2;
// then (doAB) LN->xsw in hlds region, ab GEMMs.  block = 32 rows, 4 waves.
// ---------------------------------------------------------------------------
#define HADDR(row, ch) ((((row) * 64 + ((ch) ^ ((row) & 7)))) * 8)

__global__ __launch_bounds__(256)
void ffn_ab(const _Float16* __restrict__ xln,
            const _Float16* __restrict__ w1, const float* __restrict__ b1,
            const _Float16* __restrict__ w2, const float* __restrict__ b2,
            float* __restrict__ v,
            const float* __restrict__ nlng, const float* __restrict__ nlnb,
            const _Float16* __restrict__ wa,  const float* __restrict__ ba,
            const _Float16* __restrict__ wga, const float* __restrict__ bga,
            const _Float16* __restrict__ wb,  const float* __restrict__ bb,
            const _Float16* __restrict__ wgb, const float* __restrict__ bgb,
            const _Float16* __restrict__ wgo2, const float* __restrict__ bgo2,
            _Float16* __restrict__ aout, _Float16* __restrict__ bout,
            _Float16* __restrict__ gobout, int doAB)
{
  __shared__ alignas(16) _Float16 hlds[32 * FFD];   // reused as xsw in phase D
  __shared__ float part[32][4][2];
  const int tid = threadIdx.x;
  const int lane = tid & 63;
  const int w = tid >> 6;
  const int quad = lane >> 4;
  const int l16 = lane & 15;
  const int rowBase = blockIdx.x * 32;
  const int chbase = quad * 16 + l16;

  half8 xf[2][4];
#pragma unroll
  for (int rt = 0; rt < 2; ++rt)
#pragma unroll
    for (int kt = 0; kt < 4; ++kt)
      xf[rt][kt] = *(const half8*)(xln + (size_t)(rowBase + rt * 16 + l16) * CH + kt * 32 + quad * 8);

  // phase B: h couts w*128..+128
  const half8* W1 = (const half8*)w1;
#pragma unroll
  for (int mt = 0; mt < 8; ++mt) {
    int mtg = w * 8 + mt;
    f32x4 acc[2];
    const f32x4 z = {0.f, 0.f, 0.f, 0.f};
    acc[0] = z; acc[1] = z;
#pragma unroll
    for (int kt = 0; kt < 4; ++kt) {
      half8 wf = W1[(mtg * 4 + kt) * 64 + chbase];
#pragma unroll
      for (int rt = 0; rt < 2; ++rt)
        acc[rt] = __builtin_amdgcn_mfma_f32_16x16x32_f16(wf, xf[rt][kt], acc[rt], 0, 0, 0);
    }
    f32x4 bv = *(const f32x4*)(b1 + mtg * 16 + quad * 4);
    int ch = mtg * 2 + (quad >> 1);
    int sub = (quad & 1) * 4;
#pragma unroll
    for (int rt = 0; rt < 2; ++rt) {
      int row = rt * 16 + l16;
      half4 hh;
#pragma unroll
      for (int r = 0; r < 4; ++r)
        hh[r] = (_Float16)(gelu_(acc[rt][r] + bv[r]));
      *(half4*)&hlds[HADDR(row, ch) + sub] = hh;
    }
  }
  __syncthreads();

  // phase C: out couts {2w,2w+1}, k=512 from swizzled LDS
  const half8* W2 = (const half8*)w2;
  f32x4 vn2[2][2];
  float s2[2] = {0.f, 0.f}, q2[2] = {0.f, 0.f};
#pragma unroll
  for (int m2 = 0; m2 < 2; ++m2) {
    int mt = w * 2 + m2;
    f32x4 accA[2], accB[2];
    const f32x4 z = {0.f, 0.f, 0.f, 0.f};
    accA[0] = z; accA[1] = z; accB[0] = z; accB[1] = z;
#pragma unroll
    for (int kt = 0; kt < 16; kt += 2) {
      half8 wf0 = W2[(mt * 16 + kt) * 64 + chbase];
      half8 wf1 = W2[(mt * 16 + kt + 1) * 64 + chbase];
#pragma unroll
      for (int rt = 0; rt < 2; ++rt) {
        int row = rt * 16 + l16;
        half8 hf0 = *(const half8*)&hlds[HADDR(row, kt * 4 + quad)];
        half8 hf1 = *(const half8*)&hlds[HADDR(row, (kt + 1) * 4 + quad)];
        accA[rt] = __builtin_amdgcn_mfma_f32_16x16x32_f16(wf0, hf0, accA[rt], 0, 0, 0);
        accB[rt] = __builtin_amdgcn_mfma_f32_16x16x32_f16(wf1, hf1, accB[rt], 0, 0, 0);
      }
    }
    f32x4 bv = *(const f32x4*)(b2 + mt * 16 + quad * 4);
#pragma unroll
    for (int rt = 0; rt < 2; ++rt) {
      size_t off = (size_t)(rowBase + rt * 16 + l16) * CH + mt * 16 + quad * 4;
      f32x4 vv = *(const f32x4*)(v + off);
#pragma unroll
      for (int r = 0; r < 4; ++r) {
        float nv = vv[r] + accA[rt][r] + accB[rt][r] + bv[r];
        vn2[m2][rt][r] = nv;
        s2[rt] += nv;
        q2[rt] += nv * nv;
      }
      *(f32x4*)(v + off) = vn2[m2][rt];
    }
  }
  if (!doAB) return;

#pragma unroll
  for (int rt = 0; rt < 2; ++rt) {
    float ss = s2[rt], qq = q2[rt];
    ss += __shfl_xor(ss, 16, 64); ss += __shfl_xor(ss, 32, 64);
    qq += __shfl_xor(qq, 16, 64); qq += __shfl_xor(qq, 32, 64);
    if (quad == 0) { part[rt * 16 + l16][w][0] = ss; part[rt * 16 + l16][w][1] = qq; }
  }
  __syncthreads();   // also: all hlds reads (phase C) done

  // phase D: LN -> xsw (hlds region, XADDR swizzle)
  _Float16* xsw = hlds;
#pragma unroll
  for (int rt = 0; rt < 2; ++rt) {
    int row = rt * 16 + l16;
    float su = part[row][0][0] + part[row][1][0] + part[row][2][0] + part[row][3][0];
    float qu = part[row][0][1] + part[row][1][1] + part[row][2][1] + part[row][3][1];
    float mean = su * (1.0f / 128.0f);
    float var = qu * (1.0f / 128.0f) - mean * mean;
    if (var < 0.0f) var = 0.0f;
    float rs = 1.0f / sqrtf(var + 1e-5f);
#pragma unroll
    for (int m2 = 0; m2 < 2; ++m2) {
      int mt = w * 2 + m2;
      f32x4 g4 = *(const f32x4*)(nlng + mt * 16 + quad * 4);
      f32x4 b4 = *(const f32x4*)(nlnb + mt * 16 + quad * 4);
      half4 o;
#pragma unroll
      for (int r = 0; r < 4; ++r)
        o[r] = (_Float16)((vn2[m2][rt][r] - mean) * rs * g4[r] + b4[r]);
      int ch = mt * 2 + (quad >> 1);
      *(half4*)&xsw[XADDR(row, ch) + (quad & 1) * 4] = o;
    }
  }
  __syncthreads();

  // phase E: ab GEMMs; wave w -> couts {2w, 2w+1}, rt=2 rows
  half8 xfD[2][4];
#pragma unroll
  for (int rt = 0; rt < 2; ++rt)
#pragma unroll
    for (int kt = 0; kt < 4; ++kt)
      xfD[rt][kt] = *(const half8*)&xsw[XADDR(rt * 16 + l16, kt * 4 + quad)];

  const half8* WA  = (const half8*)wa;
  const half8* WGA = (const half8*)wga;
  const half8* WB  = (const half8*)wb;
  const half8* WGB = (const half8*)wgb;
  const half8* WGO = (const half8*)wgo2;
#pragma unroll
  for (int m2 = 0; m2 < 2; ++m2) {
    int mt = w * 2 + m2;
    f32x4 aA[2], aGA[2], aB[2], aGB[2], aGO[2];
    const f32x4 z = {0.f, 0.f, 0.f, 0.f};
#pragma unroll
    for (int rt = 0; rt < 2; ++rt) { aA[rt] = z; aGA[rt] = z; aB[rt] = z; aGB[rt] = z; aGO[rt] = z; }
#pragma unroll
    for (int kt = 0; kt < 4; ++kt) {
      int ch = (mt * 4 + kt) * 64 + chbase;
      half8 wfa = WA[ch], wfga = WGA[ch], wfb = WB[ch], wfgb = WGB[ch], wfgo = WGO[ch];
#pragma unroll
      for (int rt = 0; rt < 2; ++rt) {
        aA[rt]  = __builtin_amdgcn_mfma_f32_16x16x32_f16(wfa,  xfD[rt][kt], aA[rt], 0, 0, 0);
        aGA[rt] = __builtin_amdgcn_mfma_f32_16x16x32_f16(wfga, xfD[rt][kt], aGA[rt], 0, 0, 0);
        aB[rt]  = __builtin_amdgcn_mfma_f32_16x16x32_f16(wfb,  xfD[rt][kt], aB[rt], 0, 0, 0);
        aGB[rt] = __builtin_amdgcn_mfma_f32_16x16x32_f16(wfgb, xfD[rt][kt], aGB[rt], 0, 0, 0);
        aGO[rt] = __builtin_amdgcn_mfma_f32_16x16x32_f16(wfgo, xfD[rt][kt], aGO[rt], 0, 0, 0);
      }
    }
    f32x4 bva  = *(const f32x4*)(ba   + mt * 16 + quad * 4);
    f32x4 bvga = *(const f32x4*)(bga  + mt * 16 + quad * 4);
    f32x4 bvb  = *(const f32x4*)(bb   + mt * 16 + quad * 4);
    f32x4 bvgb = *(const f32x4*)(bgb  + mt * 16 + quad * 4);
    f32x4 bvgo = *(const f32x4*)(bgo2 + mt * 16 + quad * 4);
#pragma unroll
    for (int rt = 0; rt < 2; ++rt) {
      half4 av, bv, gv;
#pragma unroll
      for (int r = 0; r < 4; ++r) {
        av[r] = (_Float16)(sigm_(aGA[rt][r] + bvga[r]) * (aA[rt][r] + bva[r]));
        bv[r] = (_Float16)(sigm_(aGB[rt][r] + bvgb[r]) * (aB[rt][r] + bvb[r]));
        gv[r] = (_Float16)(sigm_(aGO[rt][r] + bvgo[r]));
      }
      size_t off = (size_t)(rowBase + rt * 16 + l16) * CH + mt * 16 + quad * 4;
      *(half4*)(aout + off) = av;
      *(half4*)(bout + off) = bv;
      *(half4*)(gobout + off) = gv;
    }
  }
}

// ---------------------------------------------------------------------------
// final: s = v + transpose(v); e = s@decW + decb; write dense row
// ---------------------------------------------------------------------------
__global__ __launch_bounds__(256)
void decode_row(const float* __restrict__ vin, const int* __restrict__ tidx,
                const int* __restrict__ nbr, const float* __restrict__ decW,
                const float* __restrict__ decB, float* __restrict__ out)
{
  __shared__ float ev[KNN];
  __shared__ int nbr_s[KNN];
  const int n = blockIdx.x;
  const int tid = threadIdx.x;
  const int lane = tid & 63;
  const int w = tid >> 6;
  if (tid < KNN) nbr_s[tid] = nbr[n * KNN + tid];
  float dw1 = decW[lane], dw2 = decW[lane + 64];
  for (int k = w; k < KNN; k += 4) {
    int e = n * KNN + k;
    int ti = tidx[e];
    float s1 = vin[(size_t)e * CH + lane];
    float s2 = vin[(size_t)e * CH + 64 + lane];
    if (ti >= 0) {
      s1 += vin[(size_t)ti * CH + lane];
      s2 += vin[(size_t)ti * CH + 64 + lane];
    }
    float tot = wave_sum(s1 * dw1 + s2 * dw2);
    if (lane == 0) ev[k] = tot + decB[0];
  }
  __syncthreads();
  float4 z = make_float4(0.f, 0.f, 0.f, 0.f);
  float4* row = (float4*)(out + (size_t)n * NPTS);
  for (int idx = tid; idx < NPTS / 4; idx += 256) row[idx] = z;
  __syncthreads();
  if (tid < KNN) out[(size_t)n * NPTS + nbr_s[tid]] = ev[tid];
}

// ---------------------------------------------------------------------------
extern "C" void kernel_launch(void* const* d_in, const int* in_sizes, int n_in,
                              void* d_out, int out_size, void* d_ws, size_t ws_size,
                              hipStream_t stream)
{
  (void)in_sizes; (void)n_in; (void)out_size; (void)ws_size;
  const float* coords  = (const float*)d_in[0];
  const float* t_ln_g  = (const float*)d_in[1];
  const float* t_ln_b  = (const float*)d_in[2];
  const float* t_Wa    = (const float*)d_in[3];
  const float* t_ba    = (const float*)d_in[4];
  const float* t_Wga   = (const float*)d_in[5];
  const float* t_bga   = (const float*)d_in[6];
  const float* t_Wb    = (const float*)d_in[7];
  const float* t_bb    = (const float*)d_in[8];
  const float* t_Wgb   = (const float*)d_in[9];
  const float* t_bgb   = (const float*)d_in[10];
  const float* t_Wo    = (const float*)d_in[11];
  const float* t_bo    = (const float*)d_in[12];
  const float* t_Wgo   = (const float*)d_in[13];
  const float* t_bgo   = (const float*)d_in[14];
  const float* t_lno_g = (const float*)d_in[15];
  const float* t_lno_b = (const float*)d_in[16];
  const float* f_ln_g  = (const float*)d_in[17];
  const float* f_ln_b  = (const float*)d_in[18];
  const float* f_W1    = (const float*)d_in[19];
  const float* f_b1    = (const float*)d_in[20];
  const float* f_W2    = (const float*)d_in[21];
  const float* f_b2    = (const float*)d_in[22];
  const float* dec_W   = (const float*)d_in[23];
  const float* dec_b   = (const float*)d_in[24];

  const size_t NKC = (size_t)MEDGE * CH;   // 12,582,912
  char* ws = (char*)d_ws;
  float* v        = (float*)(ws);                       // 50.3 MB
  _Float16* gx    = (_Float16*)(ws + NKC * 6);          // xln / gob (row-local swap)
  int* nbr        = (int*)(ws + NKC * 8);
  int* tidx       = (int*)(ws + NKC * 8 + (size_t)MEDGE * 4);
  float4* coords4 = (float4*)(ws + NKC * 8 + (size_t)MEDGE * 8);
  _Float16* wbase = (_Float16*)(ws + NKC * 8 + (size_t)MEDGE * 8 + NPTS * 16);
  const size_t TRIH = (size_t)12 * 2048 * 8;
  _Float16* wA  = wbase;
  _Float16* wGA = wA  + TRIH;
  _Float16* wB  = wGA + TRIH;
  _Float16* wGB = wB  + TRIH;
  _Float16* wGO = wGB + TRIH;
  _Float16* wO  = wGO + TRIH;
  _Float16* w1  = wO  + TRIH;
  _Float16* w2  = w1  + (size_t)6 * 8192 * 8;

  // a/b double buffers inside d_out (free until decode_row; 100.6MB < 268MB)
  _Float16* a0 = (_Float16*)d_out;
  _Float16* b0 = a0 + NKC;
  _Float16* a1 = b0 + NKC;
  _Float16* b1 = a1 + NKC;

  prep_coords<<<32, 256, 0, stream>>>(coords, coords4);

  SwzArgs sa;
  sa.src[0] = t_Wa;  sa.dst[0] = wA;  sa.K[0] = CH;  sa.N[0] = CH;  sa.B[0] = 12; sa.perB[0] = 2048;
  sa.src[1] = t_Wga; sa.dst[1] = wGA; sa.K[1] = CH;  sa.N[1] = CH;  sa.B[1] = 12; sa.perB[1] = 2048;
  sa.src[2] = t_Wb;  sa.dst[2] = wB;  sa.K[2] = CH;  sa.N[2] = CH;  sa.B[2] = 12; sa.perB[2] = 2048;
  sa.src[3] = t_Wgb; sa.dst[3] = wGB; sa.K[3] = CH;  sa.N[3] = CH;  sa.B[3] = 12; sa.perB[3] = 2048;
  sa.src[4] = t_Wgo; sa.dst[4] = wGO; sa.K[4] = CH;  sa.N[4] = CH;  sa.B[4] = 12; sa.perB[4] = 2048;
  sa.src[5] = t_Wo;  sa.dst[5] = wO;  sa.K[5] = CH;  sa.N[5] = CH;  sa.B[5] = 12; sa.perB[5] = 2048;
  sa.src[6] = f_W1;  sa.dst[6] = w1;  sa.K[6] = CH;  sa.N[6] = FFD; sa.B[6] = 6;  sa.perB[6] = 8192;
  sa.src[7] = f_W2;  sa.dst[7] = w2;  sa.K[7] = FFD; sa.N[7] = CH;  sa.B[7] = 6;  sa.perB[7] = 8192;
  dim3 pgrid(192, 8);
  prep_weights_swz<<<pgrid, 256, 0, stream>>>(sa);

  knn_embed<<<NPTS, 256, 0, stream>>>(coords4, t_ln_g, t_ln_b, nbr, v, gx);
  build_tidx<<<MEDGE / 256, 256, 0, stream>>>(nbr, tidx);

  const size_t WS = (size_t)2048 * 8;
  gemm_ab_go<<<MEDGE / 128, 256, 0, stream>>>(gx,
      wA, t_ba, wGA, t_bga, wB, t_bb, wGB, t_bgb, wGO, t_bgo,
      a0, b0, gx);

  for (int l = 0; l < 6; ++l) {
    int s0 = 2 * l, s1 = 2 * l + 1, s2 = 2 * l + 2;
    // s0 tri + og + next (s1) a,b,gob — reads a0/b0, writes a1/b1
    tri_og_ab<<<NPTS / 4, 192, 0, stream>>>(a0, b0, nbr, tidx,
        t_lno_g + s0 * CH, t_lno_b + s0 * CH,
        wO + s0 * WS, t_bo + s0 * CH, gx, v,
        t_ln_g + s1 * CH, t_ln_b + s1 * CH,
        wA + s1 * WS, t_ba + s1 * CH, wGA + s1 * WS, t_bga + s1 * CH,
        wB + s1 * WS, t_bb + s1 * CH, wGB + s1 * WS, t_bgb + s1 * CH,
        wGO + s1 * WS, t_bgo + s1 * CH,
        a1, b1, gx, 0);
    // s1 tri + og + xln(ffn LN) — reads a1/b1
    tri_og<<<NPTS / 4, 192, 0, stream>>>(a1, b1, nbr, tidx,
        t_lno_g + s1 * CH, t_lno_b + s1 * CH,
        wO + s1 * WS, t_bo + s1 * CH, gx, v,
        f_ln_g + l * CH, f_ln_b + l * CH, gx, 1);
    // ffn + next (s2) a,b,gob — writes a0/b0
    int doAB = (l < 5) ? 1 : 0;
    int sw = doAB ? s2 : 0;
    ffn_ab<<<MEDGE / 32, 256, 0, stream>>>(gx,
        w1 + (size_t)l * 8192 * 8, f_b1 + l * FFD,
        w2 + (size_t)l * 8192 * 8, f_b2 + l * CH,
        v, t_ln_g + sw * CH, t_ln_b + sw * CH,
        wA + sw * WS, t_ba + sw * CH, wGA + sw * WS, t_bga + sw * CH,
        wB + sw * WS, t_bb + sw * CH, wGB + sw * WS, t_bgb + sw * CH,
        wGO + sw * WS, t_bgo + sw * CH,
        a0, b0, gx, doAB);
  }

  decode_row<<<NPTS, 256, 0, stream>>>(v, tidx, nbr, dec_W, dec_b, (float*)d_out);
}

// Round 10
// 2428.722 us; speedup vs baseline: 1.3463x; 1.3463x over previous
//
#include <hip/hip_runtime.h>
#include <hip/hip_bf16.h>
#include <stdint.h>
#include <stddef.h>

#define NPTS 8192
#define KNN  12
#define CH   128
#define FFD  512
#define MEDGE (NPTS * KNN)   // 98304 edges
#define NCELL 512

typedef __attribute__((ext_vector_type(8))) _Float16 half8;
typedef __attribute__((ext_vector_type(4))) _Float16 half4;
typedef __attribute__((ext_vector_type(4))) float f32x4;

__device__ __forceinline__ float wave_sum(float v) {
#pragma unroll
  for (int off = 32; off > 0; off >>= 1) v += __shfl_xor(v, off, 64);
  return v;
}
__device__ __forceinline__ float sigm_(float x) { return 1.0f / (1.0f + expf(-x)); }
__device__ __forceinline__ float gelu_(float x) { return 0.5f * x * (1.0f + erff(x * 0.7071067811865475f)); }

#define HADDR(row, ch) ((((row) * 64 + ((ch) ^ ((row) & 7)))) * 8)

// ---------------------------------------------------------------------------
// spatial sort: morton cell -> counting sort -> perm/rank
// ---------------------------------------------------------------------------
__device__ __forceinline__ int morton3(int x, int y, int z) {
  int m = 0;
#pragma unroll
  for (int b = 0; b < 3; ++b)
    m |= (((x >> b) & 1) << (3 * b + 2)) | (((y >> b) & 1) << (3 * b + 1)) | (((z >> b) & 1) << (3 * b));
  return m;
}

__global__ __launch_bounds__(512)
void zero_hist(int* __restrict__ hist)
{
  hist[threadIdx.x] = 0;
}

__global__ __launch_bounds__(256)
void prep_coords(const float* __restrict__ c, float4* __restrict__ c4,
                 int* __restrict__ cell, int* __restrict__ hist)
{
  int i = blockIdx.x * 256 + threadIdx.x;
  if (i >= NPTS) return;
  float x = c[3 * i], y = c[3 * i + 1], z = c[3 * i + 2];
  c4[i] = make_float4(x, y, z, 0.0f);
  int cx = (int)(x * (8.0f / 25.0f)); if (cx > 7) cx = 7; if (cx < 0) cx = 0;
  int cy = (int)(y * (8.0f / 25.0f)); if (cy > 7) cy = 7; if (cy < 0) cy = 0;
  int cz = (int)(z * (8.0f / 25.0f)); if (cz > 7) cz = 7; if (cz < 0) cz = 0;
  int cl = morton3(cx, cy, cz);
  cell[i] = cl;
  atomicAdd(&hist[cl], 1);
}

__global__ __launch_bounds__(512)
void prefix512(const int* __restrict__ hist, int* __restrict__ base)
{
  __shared__ int tmp[NCELL];
  int t = threadIdx.x;
  tmp[t] = hist[t];
  __syncthreads();
  for (int off = 1; off < NCELL; off <<= 1) {
    int v = tmp[t];
    if (t >= off) v += tmp[t - off];
    __syncthreads();
    tmp[t] = v;
    __syncthreads();
  }
  base[t] = tmp[t] - hist[t];   // exclusive
}

__global__ __launch_bounds__(256)
void scatter_perm(const int* __restrict__ cell, int* __restrict__ base,
                  int* __restrict__ rank, int* __restrict__ perm)
{
  int i = blockIdx.x * 256 + threadIdx.x;
  if (i >= NPTS) return;
  int r = atomicAdd(&base[cell[i]], 1);
  rank[i] = r;
  perm[r] = i;
}

// ---------------------------------------------------------------------------
// weight swizzle to MFMA A-fragment chunk order
// ---------------------------------------------------------------------------
struct SwzArgs {
  const float* src[8];
  _Float16* dst[8];
  int K[8], N[8], B[8], perB[8];
};

__global__ __launch_bounds__(256)
void prep_weights_swz(SwzArgs sa)
{
  int g = blockIdx.y;
  int idx = blockIdx.x * 256 + threadIdx.x;
  int perB = sa.perB[g];
  if (idx >= sa.B[g] * perB) return;
  int K = sa.K[g], N = sa.N[g];
  int b = idx / perB;
  int c = idx - b * perB;
  int l16 = c & 15;
  int quad = (c >> 4) & 3;
  int rest = c >> 6;
  int kts = K >> 5;
  int kt = rest % kts;
  int mt = rest / kts;
  const float* sp = sa.src[g] + ((size_t)b * K + kt * 32 + quad * 8) * N + mt * 16 + l16;
  _Float16* dp = sa.dst[g] + ((size_t)b * perB + c) * 8;
#pragma unroll
  for (int e = 0; e < 8; ++e) dp[e] = (_Float16)sp[(size_t)e * N];
}

// ---------------------------------------------------------------------------
// KNN via threshold filter + fused LN(s=0).  block = rank r; point p = perm[r].
// keys use ORIGINAL j (selection bit-identical to reference); nbr stores ranks.
// ---------------------------------------------------------------------------
#define KNN_CAP 2048

__global__ __launch_bounds__(256)
void knn_embed(const float4* __restrict__ coords4, const int* __restrict__ perm,
               const int* __restrict__ rank,
               const float* __restrict__ lng, const float* __restrict__ lnb,
               int* __restrict__ nbr, float* __restrict__ v0, _Float16* __restrict__ xln)
{
#pragma clang fp contract(off)
  __shared__ unsigned long long buf[KNN_CAP];
  __shared__ unsigned long long sel[KNN];
  __shared__ int cnt_s;
  const int i = blockIdx.x;            // rank index
  const int tid = threadIdx.x;
  const int lane = tid & 63;
  const int wv = tid >> 6;
  const float4 ci = coords4[perm[i]];

  float T2 = 9.0f;
  int cnt;
  while (true) {
    if (tid == 0) cnt_s = 0;
    __syncthreads();
    for (int j = tid; j < NPTS; j += 256) {
      float4 cj = coords4[j];
      float dx = ci.x - cj.x;
      float dy = ci.y - cj.y;
      float dz = ci.z - cj.z;
      float d2 = dx * dx + dy * dy + dz * dz;   // contract off: matches numpy
      if (d2 < T2) {
        unsigned long long key =
            (((unsigned long long)__float_as_uint(sqrtf(d2))) << 32) | (unsigned int)j;
        int idx = atomicAdd(&cnt_s, 1);
        if (idx < KNN_CAP) buf[idx] = key;
      }
    }
    __syncthreads();
    cnt = cnt_s;
    if (cnt >= KNN) break;
    T2 *= 4.0f;
    __syncthreads();
  }
  if (cnt > KNN_CAP) cnt = KNN_CAP;

  if (wv == 0) {
    unsigned long long best[KNN];
#pragma unroll
    for (int q = 0; q < KNN; ++q) best[q] = ~0ULL;
    for (int p2 = lane; p2 < cnt; p2 += 64) {
      unsigned long long key = buf[p2];
      if (key < best[KNN - 1]) {
        best[KNN - 1] = key;
#pragma unroll
        for (int q = KNN - 2; q >= 0; --q) {
          if (best[q + 1] < best[q]) { unsigned long long t = best[q]; best[q] = best[q + 1]; best[q + 1] = t; }
        }
      }
    }
    int p = 0;
    for (int r = 0; r < KNN; ++r) {
      unsigned long long c = ~0ULL;
#pragma unroll
      for (int q = 0; q < KNN; ++q) if (q == p) c = best[q];
      unsigned long long m = c;
#pragma unroll
      for (int off = 32; off > 0; off >>= 1) {
        unsigned long long o = __shfl_xor(m, off, 64);
        if (o < m) m = o;
      }
      if (c == m) ++p;
      if (lane == 0) sel[r] = m;
    }
  }
  __syncthreads();
  if (tid < KNN)
    nbr[i * KNN + tid] = rank[(int)(unsigned int)(sel[tid] & 0xFFFFFFFFULL)];

  float g1 = lng[lane], g2 = lng[lane + 64];
  float bb1 = lnb[lane], bb2 = lnb[lane + 64];
  for (int k = wv * 3; k < wv * 3 + 3; ++k) {
    float d = __uint_as_float((unsigned int)(sel[k] >> 32));
    float sig1 = (float)(1.0 + 4.0 * (double)lane / 127.0);
    float sig2 = (float)(1.0 + 4.0 * (double)(lane + 64) / 127.0);
    float e1 = expf((-(d * d)) / (2.0f * sig1 * sig1));
    float e2 = expf((-(d * d)) / (2.0f * sig2 * sig2));
    float v1 = (e1 > 0.1f) ? e1 : 0.0f;
    float v2 = (e2 > 0.1f) ? e2 : 0.0f;
    size_t off = (size_t)(i * KNN + k) * CH;
    v0[off + lane] = v1;
    v0[off + lane + 64] = v2;
    float m = wave_sum(v1 + v2) * (1.0f / 128.0f);
    float d1 = v1 - m, d2 = v2 - m;
    float var = wave_sum(d1 * d1 + d2 * d2) * (1.0f / 128.0f);
    float rs = 1.0f / sqrtf(var + 1e-5f);
    xln[off + lane]      = (_Float16)(d1 * rs * g1 + bb1);
    xln[off + lane + 64] = (_Float16)(d2 * rs * g2 + bb2);
  }
}

// ---------------------------------------------------------------------------
__global__ __launch_bounds__(256)
void build_tidx(const int* __restrict__ nbr, int* __restrict__ tidx)
{
  int e = blockIdx.x * 256 + threadIdx.x;
  if (e >= MEDGE) return;
  int i = e / KNN;
  int j = nbr[e];
  int res = -1;
#pragma unroll
  for (int t = 0; t < KNN; ++t) {
    if (nbr[j * KNN + t] == i) { res = j * KNN + t; break; }
  }
  tidx[e] = res;
}

// ---------------------------------------------------------------------------
// a, b, gob from xln (gx in/out, row-local safe). rt=2 streaming, 5 GEMMs.
// ---------------------------------------------------------------------------
__global__ __launch_bounds__(256)
void gemm_ab_go(const _Float16* __restrict__ xln,
                const _Float16* __restrict__ wa,  const float* __restrict__ ba,
                const _Float16* __restrict__ wga, const float* __restrict__ bga,
                const _Float16* __restrict__ wb,  const float* __restrict__ bb,
                const _Float16* __restrict__ wgb, const float* __restrict__ bgb,
                const _Float16* __restrict__ wgo, const float* __restrict__ bgo,
                _Float16* __restrict__ aout, _Float16* __restrict__ bout,
                _Float16* __restrict__ gobout)
{
  const int lane = threadIdx.x & 63;
  const int quad = lane >> 4;
  const int l16 = lane & 15;
  const int gw = blockIdx.x * 4 + (threadIdx.x >> 6);
  const int base = gw * 32;
  const int chbase = quad * 16 + l16;

  half8 xf[2][4];
#pragma unroll
  for (int rt = 0; rt < 2; ++rt)
#pragma unroll
    for (int kt = 0; kt < 4; ++kt)
      xf[rt][kt] = *(const half8*)(xln + (size_t)(base + rt * 16 + l16) * CH + kt * 32 + quad * 8);

  const half8* WA  = (const half8*)wa;
  const half8* WGA = (const half8*)wga;
  const half8* WB  = (const half8*)wb;
  const half8* WGB = (const half8*)wgb;
  const half8* WGO = (const half8*)wgo;

#pragma unroll
  for (int mt = 0; mt < 8; ++mt) {
    f32x4 aA[2], aGA[2], aB[2], aGB[2], aGO[2];
    const f32x4 z = {0.f, 0.f, 0.f, 0.f};
#pragma unroll
    for (int rt = 0; rt < 2; ++rt) { aA[rt] = z; aGA[rt] = z; aB[rt] = z; aGB[rt] = z; aGO[rt] = z; }
#pragma unroll
    for (int kt = 0; kt < 4; ++kt) {
      int ch = (mt * 4 + kt) * 64 + chbase;
      half8 wfa = WA[ch], wfga = WGA[ch], wfb = WB[ch], wfgb = WGB[ch], wfgo = WGO[ch];
#pragma unroll
      for (int rt = 0; rt < 2; ++rt) {
        aA[rt]  = __builtin_amdgcn_mfma_f32_16x16x32_f16(wfa,  xf[rt][kt], aA[rt], 0, 0, 0);
        aGA[rt] = __builtin_amdgcn_mfma_f32_16x16x32_f16(wfga, xf[rt][kt], aGA[rt], 0, 0, 0);
        aB[rt]  = __builtin_amdgcn_mfma_f32_16x16x32_f16(wfb,  xf[rt][kt], aB[rt], 0, 0, 0);
        aGB[rt] = __builtin_amdgcn_mfma_f32_16x16x32_f16(wfgb, xf[rt][kt], aGB[rt], 0, 0, 0);
        aGO[rt] = __builtin_amdgcn_mfma_f32_16x16x32_f16(wfgo, xf[rt][kt], aGO[rt], 0, 0, 0);
      }
    }
    f32x4 bva  = *(const f32x4*)(ba  + mt * 16 + quad * 4);
    f32x4 bvga = *(const f32x4*)(bga + mt * 16 + quad * 4);
    f32x4 bvb  = *(const f32x4*)(bb  + mt * 16 + quad * 4);
    f32x4 bvgb = *(const f32x4*)(bgb + mt * 16 + quad * 4);
    f32x4 bvgo = *(const f32x4*)(bgo + mt * 16 + quad * 4);
#pragma unroll
    for (int rt = 0; rt < 2; ++rt) {
      half4 av, bv, gv;
#pragma unroll
      for (int r = 0; r < 4; ++r) {
        av[r] = (_Float16)(sigm_(aGA[rt][r] + bvga[r]) * (aA[rt][r] + bva[r]));
        bv[r] = (_Float16)(sigm_(aGB[rt][r] + bvgb[r]) * (aB[rt][r] + bvb[r]));
        gv[r] = (_Float16)(sigm_(aGO[rt][r] + bvgo[r]));
      }
      size_t off = (size_t)(base + rt * 16 + l16) * CH + mt * 16 + quad * 4;
      *(half4*)(aout + off) = av;
      *(half4*)(bout + off) = bv;
      *(half4*)(gobout + off) = gv;
    }
  }
}

// ---------------------------------------------------------------------------
// tri einsum + LN -> klds ; og residual ; xln write.  XCD-chunk swizzle.
// ---------------------------------------------------------------------------
__global__ __launch_bounds__(192)
void tri_og(const _Float16* __restrict__ a, const _Float16* __restrict__ b,
            const int* __restrict__ nbr, const int* __restrict__ tidx,
            const float* __restrict__ lng, const float* __restrict__ lnb,
            const _Float16* __restrict__ wo, const float* __restrict__ bo,
            const _Float16* __restrict__ gob, float* __restrict__ v,
            const float* __restrict__ nlng, const float* __restrict__ nlnb,
            _Float16* __restrict__ xlnN, int incoming)
{
  __shared__ alignas(16) _Float16 As[48][136];
  __shared__ alignas(16) _Float16 klds[48][136];
  __shared__ int bidx[4][KNN][KNN];
  __shared__ int nbr_s[4][KNN];
  // XCD-chunk swizzle: blk%8 -> XCD (heuristic); each XCD gets contiguous 1024 pts
  const int blk = blockIdx.x;
  const int n0 = ((blk & 7) * 256 + (blk >> 3)) * 4;
  const int tid = threadIdx.x;

  if (tid < 48) nbr_s[tid / KNN][tid % KNN] = nbr[n0 * KNN + tid];
  __syncthreads();
  for (int it = tid; it < 4 * KNN * KNN; it += 192) {
    int nn = it / (KNN * KNN);
    int r = it - nn * KNN * KNN;
    int m = r / KNN, t = r - m * KNN;
    int j = nbr_s[nn][m];
    bidx[nn][m][t] = incoming ? tidx[j * KNN + t] : (j * KNN + t);
  }
  for (int it = tid; it < 4 * KNN * 16; it += 192) {
    int nn = it / (KNN * 16);
    int r = it - nn * (KNN * 16);
    int t = r >> 4;
    int c8 = (r & 15) * 8;
    half8 av;
    if (incoming) {
      int ti = tidx[(size_t)(n0 + nn) * KNN + t];
      if (ti >= 0) av = *(const half8*)(a + (size_t)ti * CH + c8);
      else {
#pragma unroll
        for (int e = 0; e < 8; ++e) av[e] = (_Float16)0.0f;
      }
    } else {
      av = *(const half8*)(a + (size_t)((n0 + nn) * KNN + t) * CH + c8);
    }
    *(half8*)&As[nn * KNN + t][c8] = av;
  }
  __syncthreads();

  const int m2 = tid >> 4;
  const int c8 = (tid & 15) * 8;
  for (int nn = 0; nn < 4; ++nn) {
    float acc[8];
#pragma unroll
    for (int r = 0; r < 8; ++r) acc[r] = 0.0f;
#pragma unroll
    for (int t = 0; t < KNN; ++t) {
      int bi = bidx[nn][m2][t];
      if (bi >= 0) {
        half8 bv = *(const half8*)(b + (size_t)bi * CH + c8);
        half8 av = *(const half8*)&As[nn * KNN + t][c8];
#pragma unroll
        for (int r = 0; r < 8; ++r) acc[r] += (float)av[r] * (float)bv[r];
      }
    }
    float s = 0.0f, sq = 0.0f;
#pragma unroll
    for (int r = 0; r < 8; ++r) { s += acc[r]; sq += acc[r] * acc[r]; }
#pragma unroll
    for (int off = 1; off < 16; off <<= 1) {
      s += __shfl_xor(s, off, 64);
      sq += __shfl_xor(sq, off, 64);
    }
    float mean = s * (1.0f / 128.0f);
    float var = sq * (1.0f / 128.0f) - mean * mean;
    if (var < 0.0f) var = 0.0f;
    float rs = 1.0f / sqrtf(var + 1e-5f);
    half8 o;
#pragma unroll
    for (int r = 0; r < 8; ++r)
      o[r] = (_Float16)((acc[r] - mean) * rs * lng[c8 + r] + lnb[c8 + r]);
    *(half8*)&klds[nn * KNN + m2][c8] = o;
  }
  __syncthreads();

  const int lane = tid & 63;
  const int w = tid >> 6;
  const int quad = lane >> 4;
  const int l16 = lane & 15;
  const int chbase = quad * 16 + l16;
  const size_t rowOff = (size_t)(n0 * KNN + w * 16 + l16) * CH;

  half8 kf[4];
#pragma unroll
  for (int kt = 0; kt < 4; ++kt)
    kf[kt] = *(const half8*)&klds[w * 16 + l16][kt * 32 + quad * 8];

  const half8* WO = (const half8*)wo;
  f32x4 vn[8];
  float s = 0.0f, sq = 0.0f;
#pragma unroll
  for (int mt = 0; mt < 8; ++mt) {
    f32x4 acc = {0.f, 0.f, 0.f, 0.f};
#pragma unroll
    for (int kt = 0; kt < 4; ++kt)
      acc = __builtin_amdgcn_mfma_f32_16x16x32_f16(WO[(mt * 4 + kt) * 64 + chbase], kf[kt], acc, 0, 0, 0);
    half4 g4 = *(const half4*)(gob + rowOff + mt * 16 + quad * 4);
    f32x4 bo4 = *(const f32x4*)(bo + mt * 16 + quad * 4);
    f32x4 vv = *(const f32x4*)(v + rowOff + mt * 16 + quad * 4);
#pragma unroll
    for (int r = 0; r < 4; ++r) {
      float nv = vv[r] + (float)g4[r] * (acc[r] + bo4[r]);
      vn[mt][r] = nv;
      s += nv;
      sq += nv * nv;
    }
    *(f32x4*)(v + rowOff + mt * 16 + quad * 4) = vn[mt];
  }
  s  += __shfl_xor(s, 16, 64);  s  += __shfl_xor(s, 32, 64);
  sq += __shfl_xor(sq, 16, 64); sq += __shfl_xor(sq, 32, 64);
  float mean = s * (1.0f / 128.0f);
  float var = sq * (1.0f / 128.0f) - mean * mean;
  if (var < 0.0f) var = 0.0f;
  float rs = 1.0f / sqrtf(var + 1e-5f);
#pragma unroll
  for (int mt = 0; mt < 8; ++mt) {
    f32x4 g4 = *(const f32x4*)(nlng + mt * 16 + quad * 4);
    f32x4 b4 = *(const f32x4*)(nlnb + mt * 16 + quad * 4);
    half4 o;
#pragma unroll
    for (int r = 0; r < 4; ++r)
      o[r] = (_Float16)((vn[mt][r] - mean) * rs * g4[r] + b4[r]);
    *(half4*)(xlnN + rowOff + mt * 16 + quad * 4) = o;
  }
}

// ---------------------------------------------------------------------------
// fused FFN: h in XOR-swizzled LDS; v += h@W2 + b2; xln_next = LN(v)*g+b.
// ---------------------------------------------------------------------------
__global__ __launch_bounds__(256)
void ffn_fused(const _Float16* __restrict__ xln,
               const _Float16* __restrict__ w1, const float* __restrict__ b1,
               const _Float16* __restrict__ w2, const float* __restrict__ b2,
               float* __restrict__ v,
               const float* __restrict__ nlng, const float* __restrict__ nlnb,
               _Float16* __restrict__ xlnN)
{
  __shared__ alignas(16) _Float16 hlds[32 * FFD];
  __shared__ float part[32][4][2];
  const int tid = threadIdx.x;
  const int lane = tid & 63;
  const int w = tid >> 6;
  const int quad = lane >> 4;
  const int l16 = lane & 15;
  const int rowBase = blockIdx.x * 32;
  const int chbase = quad * 16 + l16;

  half8 xf[2][4];
#pragma unroll
  for (int rt = 0; rt < 2; ++rt)
#pragma unroll
    for (int kt = 0; kt < 4; ++kt)
      xf[rt][kt] = *(const half8*)(xln + (size_t)(rowBase + rt * 16 + l16) * CH + kt * 32 + quad * 8);

  const half8* W1 = (const half8*)w1;
#pragma unroll
  for (int mt = 0; mt < 8; ++mt) {
    int mtg = w * 8 + mt;
    f32x4 acc[2];
    const f32x4 z = {0.f, 0.f, 0.f, 0.f};
    acc[0] = z; acc[1] = z;
#pragma unroll
    for (int kt = 0; kt < 4; ++kt) {
      half8 wf = W1[(mtg * 4 + kt) * 64 + chbase];
#pragma unroll
      for (int rt = 0; rt < 2; ++rt)
        acc[rt] = __builtin_amdgcn_mfma_f32_16x16x32_f16(wf, xf[rt][kt], acc[rt], 0, 0, 0);
    }
    f32x4 bv = *(const f32x4*)(b1 + mtg * 16 + quad * 4);
    int ch = mtg * 2 + (quad >> 1);
    int sub = (quad & 1) * 4;
#pragma unroll
    for (int rt = 0; rt < 2; ++rt) {
      int row = rt * 16 + l16;
      half4 hh;
#pragma unroll
      for (int r = 0; r < 4; ++r)
        hh[r] = (_Float16)(gelu_(acc[rt][r] + bv[r]));
      *(half4*)&hlds[HADDR(row, ch) + sub] = hh;
    }
  }
  __syncthreads();

  const half8* W2 = (const half8*)w2;
  f32x4 vn2[2][2];
  float s2[2] = {0.f, 0.f}, q2[2] = {0.f, 0.f};
#pragma unroll
  for (int m2 = 0; m2 < 2; ++m2) {
    int mt = w * 2 + m2;
    f32x4 accA[2], accB[2];
    const f32x4 z = {0.f, 0.f, 0.f, 0.f};
    accA[0] = z; accA[1] = z; accB[0] = z; accB[1] = z;
#pragma unroll
    for (int kt = 0; kt < 16; kt += 2) {
      half8 wf0 = W2[(mt * 16 + kt) * 64 + chbase];
      half8 wf1 = W2[(mt * 16 + kt + 1) * 64 + chbase];
#pragma unroll
      for (int rt = 0; rt < 2; ++rt) {
        int row = rt * 16 + l16;
        half8 hf0 = *(const half8*)&hlds[HADDR(row, kt * 4 + quad)];
        half8 hf1 = *(const half8*)&hlds[HADDR(row, (kt + 1) * 4 + quad)];
        accA[rt] = __builtin_amdgcn_mfma_f32_16x16x32_f16(wf0, hf0, accA[rt], 0, 0, 0);
        accB[rt] = __builtin_amdgcn_mfma_f32_16x16x32_f16(wf1, hf1, accB[rt], 0, 0, 0);
      }
    }
    f32x4 bv = *(const f32x4*)(b2 + mt * 16 + quad * 4);
#pragma unroll
    for (int rt = 0; rt < 2; ++rt) {
      size_t off = (size_t)(rowBase + rt * 16 + l16) * CH + mt * 16 + quad * 4;
      f32x4 vv = *(const f32x4*)(v + off);
#pragma unroll
      for (int r = 0; r < 4; ++r) {
        float nv = vv[r] + accA[rt][r] + accB[rt][r] + bv[r];
        vn2[m2][rt][r] = nv;
        s2[rt] += nv;
        q2[rt] += nv * nv;
      }
      *(f32x4*)(v + off) = vn2[m2][rt];
    }
  }
#pragma unroll
  for (int rt = 0; rt < 2; ++rt) {
    float ss = s2[rt], qq = q2[rt];
    ss += __shfl_xor(ss, 16, 64); ss += __shfl_xor(ss, 32, 64);
    qq += __shfl_xor(qq, 16, 64); qq += __shfl_xor(qq, 32, 64);
    if (quad == 0) { part[rt * 16 + l16][w][0] = ss; part[rt * 16 + l16][w][1] = qq; }
  }
  __syncthreads();
#pragma unroll
  for (int rt = 0; rt < 2; ++rt) {
    int row = rt * 16 + l16;
    float su = part[row][0][0] + part[row][1][0] + part[row][2][0] + part[row][3][0];
    float qu = part[row][0][1] + part[row][1][1] + part[row][2][1] + part[row][3][1];
    float mean = su * (1.0f / 128.0f);
    float var = qu * (1.0f / 128.0f) - mean * mean;
    if (var < 0.0f) var = 0.0f;
    float rs = 1.0f / sqrtf(var + 1e-5f);
#pragma unroll
    for (int m2 = 0; m2 < 2; ++m2) {
      int mt = w * 2 + m2;
      f32x4 g4 = *(const f32x4*)(nlng + mt * 16 + quad * 4);
      f32x4 b4 = *(const f32x4*)(nlnb + mt * 16 + quad * 4);
      half4 o;
#pragma unroll
      for (int r = 0; r < 4; ++r)
        o[r] = (_Float16)((vn2[m2][rt][r] - mean) * rs * g4[r] + b4[r]);
      *(half4*)(xlnN + (size_t)(rowBase + row) * CH + mt * 16 + quad * 4) = o;
    }
  }
}

// ---------------------------------------------------------------------------
// final: s = v + transpose(v); e = s@decW + decb; write dense row (orig index)
// ---------------------------------------------------------------------------
__global__ __launch_bounds__(256)
void decode_row(const float* __restrict__ vin, const int* __restrict__ tidx,
                const int* __restrict__ nbr, const int* __restrict__ perm,
                const float* __restrict__ decW, const float* __restrict__ decB,
                float* __restrict__ out)
{
  __shared__ float ev[KNN];
  __shared__ int col_s[KNN];
  const int n = blockIdx.x;            // rank index
  const int tid = threadIdx.x;
  const int lane = tid & 63;
  const int w = tid >> 6;
  if (tid < KNN) col_s[tid] = perm[nbr[n * KNN + tid]];
  float dw1 = decW[lane], dw2 = decW[lane + 64];
  for (int k = w; k < KNN; k += 4) {
    int e = n * KNN + k;
    int ti = tidx[e];
    float s1 = vin[(size_t)e * CH + lane];
    float s2 = vin[(size_t)e * CH + 64 + lane];
    if (ti >= 0) {
      s1 += vin[(size_t)ti * CH + lane];
      s2 += vin[(size_t)ti * CH + 64 + lane];
    }
    float tot = wave_sum(s1 * dw1 + s2 * dw2);
    if (lane == 0) ev[k] = tot + decB[0];
  }
  __syncthreads();
  const int orig_n = perm[n];
  float4 z = make_float4(0.f, 0.f, 0.f, 0.f);
  float4* row = (float4*)(out + (size_t)orig_n * NPTS);
  for (int idx = tid; idx < NPTS / 4; idx += 256) row[idx] = z;
  __syncthreads();
  if (tid < KNN) out[(size_t)orig_n * NPTS + col_s[tid]] = ev[tid];
}

// ---------------------------------------------------------------------------
extern "C" void kernel_launch(void* const* d_in, const int* in_sizes, int n_in,
                              void* d_out, int out_size, void* d_ws, size_t ws_size,
                              hipStream_t stream)
{
  (void)in_sizes; (void)n_in; (void)out_size; (void)ws_size;
  const float* coords  = (const float*)d_in[0];
  const float* t_ln_g  = (const float*)d_in[1];
  const float* t_ln_b  = (const float*)d_in[2];
  const float* t_Wa    = (const float*)d_in[3];
  const float* t_ba    = (const float*)d_in[4];
  const float* t_Wga   = (const float*)d_in[5];
  const float* t_bga   = (const float*)d_in[6];
  const float* t_Wb    = (const float*)d_in[7];
  const float* t_bb    = (const float*)d_in[8];
  const float* t_Wgb   = (const float*)d_in[9];
  const float* t_bgb   = (const float*)d_in[10];
  const float* t_Wo    = (const float*)d_in[11];
  const float* t_bo    = (const float*)d_in[12];
  const float* t_Wgo   = (const float*)d_in[13];
  const float* t_bgo   = (const float*)d_in[14];
  const float* t_lno_g = (const float*)d_in[15];
  const float* t_lno_b = (const float*)d_in[16];
  const float* f_ln_g  = (const float*)d_in[17];
  const float* f_ln_b  = (const float*)d_in[18];
  const float* f_W1    = (const float*)d_in[19];
  const float* f_b1    = (const float*)d_in[20];
  const float* f_W2    = (const float*)d_in[21];
  const float* f_b2    = (const float*)d_in[22];
  const float* dec_W   = (const float*)d_in[23];
  const float* dec_b   = (const float*)d_in[24];

  const size_t NKC = (size_t)MEDGE * CH;   // 12,582,912
  char* ws = (char*)d_ws;
  float* v        = (float*)(ws);                       // 50.3 MB
  _Float16* gx    = (_Float16*)(ws + NKC * 6);          // xln / gob (row-local swap)
  int* nbr        = (int*)(ws + NKC * 8);
  int* tidx       = (int*)(ws + NKC * 8 + (size_t)MEDGE * 4);
  char* aux       = ws + NKC * 8 + (size_t)MEDGE * 8;
  float4* coords4 = (float4*)(aux);
  int* cell       = (int*)(aux + NPTS * 16);
  int* hist       = (int*)(aux + NPTS * 16 + NPTS * 4);
  int* base       = (int*)(aux + NPTS * 16 + NPTS * 4 + NCELL * 4);
  int* rank       = (int*)(aux + NPTS * 16 + NPTS * 4 + NCELL * 8);
  int* perm       = (int*)(aux + NPTS * 16 + NPTS * 8 + NCELL * 8);
  _Float16* wbase = (_Float16*)(aux + NPTS * 16 + NPTS * 12 + NCELL * 8);
  const size_t TRIH = (size_t)12 * 2048 * 8;
  _Float16* wA  = wbase;
  _Float16* wGA = wA  + TRIH;
  _Float16* wB  = wGA + TRIH;
  _Float16* wGB = wB  + TRIH;
  _Float16* wGO = wGB + TRIH;
  _Float16* wO  = wGO + TRIH;
  _Float16* w1  = wO  + TRIH;
  _Float16* w2  = w1  + (size_t)6 * 8192 * 8;

  // scratch inside d_out (free until decode_row)
  _Float16* abuf = (_Float16*)d_out;
  _Float16* bbuf = abuf + NKC;

  zero_hist<<<1, 512, 0, stream>>>(hist);
  prep_coords<<<32, 256, 0, stream>>>(coords, coords4, cell, hist);
  prefix512<<<1, 512, 0, stream>>>(hist, base);
  scatter_perm<<<32, 256, 0, stream>>>(cell, base, rank, perm);

  SwzArgs sa;
  sa.src[0] = t_Wa;  sa.dst[0] = wA;  sa.K[0] = CH;  sa.N[0] = CH;  sa.B[0] = 12; sa.perB[0] = 2048;
  sa.src[1] = t_Wga; sa.dst[1] = wGA; sa.K[1] = CH;  sa.N[1] = CH;  sa.B[1] = 12; sa.perB[1] = 2048;
  sa.src[2] = t_Wb;  sa.dst[2] = wB;  sa.K[2] = CH;  sa.N[2] = CH;  sa.B[2] = 12; sa.perB[2] = 2048;
  sa.src[3] = t_Wgb; sa.dst[3] = wGB; sa.K[3] = CH;  sa.N[3] = CH;  sa.B[3] = 12; sa.perB[3] = 2048;
  sa.src[4] = t_Wgo; sa.dst[4] = wGO; sa.K[4] = CH;  sa.N[4] = CH;  sa.B[4] = 12; sa.perB[4] = 2048;
  sa.src[5] = t_Wo;  sa.dst[5] = wO;  sa.K[5] = CH;  sa.N[5] = CH;  sa.B[5] = 12; sa.perB[5] = 2048;
  sa.src[6] = f_W1;  sa.dst[6] = w1;  sa.K[6] = CH;  sa.N[6] = FFD; sa.B[6] = 6;  sa.perB[6] = 8192;
  sa.src[7] = f_W2;  sa.dst[7] = w2;  sa.K[7] = FFD; sa.N[7] = CH;  sa.B[7] = 6;  sa.perB[7] = 8192;
  dim3 pgrid(192, 8);
  prep_weights_swz<<<pgrid, 256, 0, stream>>>(sa);

  knn_embed<<<NPTS, 256, 0, stream>>>(coords4, perm, rank, t_ln_g, t_ln_b, nbr, v, gx);
  build_tidx<<<MEDGE / 256, 256, 0, stream>>>(nbr, tidx);

  const size_t WS = (size_t)2048 * 8;
  gemm_ab_go<<<MEDGE / 128, 256, 0, stream>>>(gx,
      wA, t_ba, wGA, t_bga, wB, t_bb, wGB, t_bgb, wGO, t_bgo,
      abuf, bbuf, gx);

  for (int l = 0; l < 6; ++l) {
    int s0 = 2 * l, s1 = 2 * l + 1, s2 = 2 * l + 2;
    tri_og<<<NPTS / 4, 192, 0, stream>>>(abuf, bbuf, nbr, tidx,
        t_lno_g + s0 * CH, t_lno_b + s0 * CH,
        wO + s0 * WS, t_bo + s0 * CH, gx, v,
        t_ln_g + s1 * CH, t_ln_b + s1 * CH, gx, 0);
    gemm_ab_go<<<MEDGE / 128, 256, 0, stream>>>(gx,
        wA + s1 * WS, t_ba + s1 * CH, wGA + s1 * WS, t_bga + s1 * CH,
        wB + s1 * WS, t_bb + s1 * CH, wGB + s1 * WS, t_bgb + s1 * CH,
        wGO + s1 * WS, t_bgo + s1 * CH,
        abuf, bbuf, gx);
    tri_og<<<NPTS / 4, 192, 0, stream>>>(abuf, bbuf, nbr, tidx,
        t_lno_g + s1 * CH, t_lno_b + s1 * CH,
        wO + s1 * WS, t_bo + s1 * CH, gx, v,
        f_ln_g + l * CH, f_ln_b + l * CH, gx, 1);
    const float* ng = (l < 5) ? (t_ln_g + s2 * CH) : t_ln_g;
    const float* nb = (l < 5) ? (t_ln_b + s2 * CH) : t_ln_b;
    ffn_fused<<<MEDGE / 32, 256, 0, stream>>>(gx,
        w1 + (size_t)l * 8192 * 8, f_b1 + l * FFD,
        w2 + (size_t)l * 8192 * 8, f_b2 + l * CH,
        v, ng, nb, gx);
    if (l < 5) {
      gemm_ab_go<<<MEDGE / 128, 256, 0, stream>>>(gx,
          wA + s2 * WS, t_ba + s2 * CH, wGA + s2 * WS, t_bga + s2 * CH,
          wB + s2 * WS, t_bb + s2 * CH, wGB + s2 * WS, t_bgb + s2 * CH,
          wGO + s2 * WS, t_bgo + s2 * CH,
          abuf, bbuf, gx);
    }
  }

  decode_row<<<NPTS, 256, 0, stream>>>(v, tidx, nbr, perm, dec_W, dec_b, (float*)d_out);
}